// Round 7
// baseline (295.142 us; speedup 1.0000x reference)
//
#include <hip/hip_runtime.h>
#include <math.h>

#define F 64
#define NPB 160        // nodes per bucket
#define BCAP 3584      // per-bucket capacity in binned (mean 2560, +20 sigma)
#define SSTRIDE 4096   // fixed ssrc region per bucket (>= BCAP + 3*NPB = 4064)
#define STAGE_N 4096

typedef __attribute__((ext_vector_type(8))) short bf16x8;
typedef __attribute__((ext_vector_type(4))) float f32x4;

__device__ inline unsigned short f2bf(float f) {
  unsigned int u = __float_as_uint(f);
  u += 0x7fffu + ((u >> 16) & 1u);   // round-to-nearest-even
  return (unsigned short)(u >> 16);
}

// ---------------- prep: W fragment pack (block 0) + bcnt zero + out init ----------------
__global__ __launch_bounds__(256) void k_prep(const float* __restrict__ W1, const float* __restrict__ W2,
                                              uint4* __restrict__ wf, int* __restrict__ bcnt, int nb,
                                              float* __restrict__ out, const float* __restrict__ bo, int ng,
                                              int* __restrict__ ssrc) {
  int tid = threadIdx.x;
  if (blockIdx.x == 0) {
    // pack W1/W2 into MFMA B-fragment layout: wf[layer*512 + (c*2+kk)*64 + lane] = 8 bf16 (j=0..7)
    for (int i = tid; i < 1024; i += 256) {
      int layer = i >> 9, rem = i & 511;
      int cb = rem >> 6, lane = rem & 63;
      int c = cb >> 1, kk = cb & 1;
      int l15 = lane & 15, quad = lane >> 4;
      const float* W = layer ? W2 : W1;
      unsigned short p[8];
      #pragma unroll
      for (int j = 0; j < 8; j++) {
        int kd = kk * 32 + quad * 8 + j;
        p[j] = f2bf(W[kd * F + c * 16 + l15]);
      }
      wf[i] = *(const uint4*)p;
    }
  } else {
    for (int i = tid; i < nb * 16; i += 256) bcnt[i] = 0;  // counters padded to 64B lines
    float b0 = bo[0];
    for (int i = tid; i < ng; i += 256) out[i] = b0;
    if (tid < 64) ssrc[tid] = 0;                           // head slack (deg-0 reads)
  }
}

// ---------------- MFMA GEMM body: fp32 input rows -> bf16 h + als/ald ----------------
__device__ __forceinline__ void gemm_body(const float* __restrict__ in, const uint4* __restrict__ wf,
                                          const float* __restrict__ avs, const float* __restrict__ avd,
                                          unsigned short* __restrict__ hgb, float* __restrict__ als,
                                          float* __restrict__ ald, int n, int bid, int nbl) {
  int tid = threadIdx.x, lane = tid & 63, wv = tid >> 6;
  int l15 = lane & 15, quad = lane >> 4;
  bf16x8 bfr[4][2];
  #pragma unroll
  for (int cb = 0; cb < 8; cb++) {
    uint4 u = wf[cb * 64 + lane];
    bfr[cb >> 1][cb & 1] = *(const bf16x8*)&u;
  }
  float as_l[4], ad_l[4];
  #pragma unroll
  for (int c = 0; c < 4; c++) { as_l[c] = avs[c * 16 + l15]; ad_l[c] = avd[c * 16 + l15]; }

  int nchunks = n >> 6;
  for (int chunk = bid; chunk < nchunks; chunk += nbl) {
    int r0 = (chunk << 6) + (wv << 4);
    bf16x8 a0, a1;
    const float4* xr = (const float4*)(in + (size_t)(r0 + l15) * F + quad * 8);
    float4 xa = xr[0], xb = xr[1];
    float4 xc = xr[8], xd = xr[9];
    a0[0] = (short)f2bf(xa.x); a0[1] = (short)f2bf(xa.y); a0[2] = (short)f2bf(xa.z); a0[3] = (short)f2bf(xa.w);
    a0[4] = (short)f2bf(xb.x); a0[5] = (short)f2bf(xb.y); a0[6] = (short)f2bf(xb.z); a0[7] = (short)f2bf(xb.w);
    a1[0] = (short)f2bf(xc.x); a1[1] = (short)f2bf(xc.y); a1[2] = (short)f2bf(xc.z); a1[3] = (short)f2bf(xc.w);
    a1[4] = (short)f2bf(xd.x); a1[5] = (short)f2bf(xd.y); a1[6] = (short)f2bf(xd.z); a1[7] = (short)f2bf(xd.w);
    f32x4 cfr[4];
    #pragma unroll
    for (int c = 0; c < 4; c++) {
      cfr[c] = (f32x4){0.f, 0.f, 0.f, 0.f};
      cfr[c] = __builtin_amdgcn_mfma_f32_16x16x32_bf16(a0, bfr[c][0], cfr[c], 0, 0, 0);
      cfr[c] = __builtin_amdgcn_mfma_f32_16x16x32_bf16(a1, bfr[c][1], cfr[c], 0, 0, 0);
    }
    #pragma unroll
    for (int i = 0; i < 4; i++) {
      int row = r0 + quad * 4 + i;
      #pragma unroll
      for (int c = 0; c < 4; c++) hgb[(size_t)row * F + c * 16 + l15] = f2bf(cfr[c][i]);
      float ps = cfr[0][i] * as_l[0] + cfr[1][i] * as_l[1] + cfr[2][i] * as_l[2] + cfr[3][i] * as_l[3];
      float pd = cfr[0][i] * ad_l[0] + cfr[1][i] * ad_l[1] + cfr[2][i] * ad_l[2] + cfr[3][i] * ad_l[3];
      #pragma unroll
      for (int o = 1; o <= 8; o <<= 1) { ps += __shfl_xor(ps, o); pd += __shfl_xor(pd, o); }
      if (l15 == 0) { als[row] = ps; ald[row] = pd; }
    }
  }
}

// ---------------- fused: bucketed scatter (blocks < S) + layer-1 GEMM ----------------
__global__ __launch_bounds__(256) void k_scatter_gemm1(const int* __restrict__ esrc, const int* __restrict__ edst,
                                                       int* __restrict__ bcnt, unsigned int* __restrict__ binned,
                                                       int e, int ch, int S,
                                                       const float* __restrict__ x, const uint4* __restrict__ wf,
                                                       const float* __restrict__ avs, const float* __restrict__ avd,
                                                       unsigned short* __restrict__ hgb, float* __restrict__ als,
                                                       float* __restrict__ ald, int n) {
  int k = blockIdx.x, tid = threadIdx.x;
  if (k < S) {
    __shared__ int hist[1024];
    __shared__ int cur[1024];
    for (int i = tid; i < 1024; i += 256) hist[i] = 0;
    __syncthreads();
    int beg = k * ch, end = min(e, beg + ch);
    int len = end - beg;
    if (len <= 0) return;
    int nv = len >> 2;  // beg is 16B-aligned (ch multiple of 4)
    // phase A: histogram
    for (int g = tid; g < nv; g += 256) {
      int4 d4 = *(const int4*)(edst + beg + (g << 2));
      atomicAdd(&hist[d4.x / NPB], 1);
      atomicAdd(&hist[d4.y / NPB], 1);
      atomicAdd(&hist[d4.z / NPB], 1);
      atomicAdd(&hist[d4.w / NPB], 1);
    }
    for (int i = beg + (nv << 2) + tid; i < end; i += 256) atomicAdd(&hist[edst[i] / NPB], 1);
    __syncthreads();
    // phase B: reserve per-bucket runs (global atomics on padded counters)
    for (int b = tid; b < 1024; b += 256) {
      int c = hist[b];
      int base = 0;
      if (c) base = atomicAdd(&bcnt[b * 16], c);
      cur[b] = b * BCAP + base;
    }
    __syncthreads();
    // phase C: place
    for (int g = tid; g < nv; g += 256) {
      int i = beg + (g << 2);
      int4 d4 = *(const int4*)(edst + i);
      int4 s4 = *(const int4*)(esrc + i);
      #pragma unroll
      for (int j = 0; j < 4; j++) {
        int d = (j == 0) ? d4.x : (j == 1) ? d4.y : (j == 2) ? d4.z : d4.w;
        int s = (j == 0) ? s4.x : (j == 1) ? s4.y : (j == 2) ? s4.z : s4.w;
        int b = d / NPB;
        int p = atomicAdd(&cur[b], 1);
        if (p < (b + 1) * BCAP) binned[p] = (unsigned int)s | ((unsigned int)(d - b * NPB) << 24);
      }
    }
    for (int i = beg + (nv << 2) + tid; i < end; i += 256) {
      int d = edst[i];
      int b = d / NPB;
      int p = atomicAdd(&cur[b], 1);
      if (p < (b + 1) * BCAP) binned[p] = (unsigned int)esrc[i] | ((unsigned int)(d - b * NPB) << 24);
    }
    return;
  }
  gemm_body(x, wf, avs, avd, hgb, als, ald, n, k - S, (int)gridDim.x - S);
}

// one block per bucket: per-node counting sort into 4-padded segments within the bucket's
// fixed SSTRIDE region (no cross-bucket prefix needed). Pads are zero (node 0), masked by
// deg from ndeg[]. Emits offs (16B-aligned bases) + ndeg.
__global__ __launch_bounds__(256) void k_bucket_csr(const unsigned int* __restrict__ binned,
                                                    const int* __restrict__ bcnt,
                                                    int* __restrict__ ssrc, int* __restrict__ offs,
                                                    int* __restrict__ ndeg, int n) {
  __shared__ int ncnt[NPB];
  __shared__ int cur[NPB];
  __shared__ int wsum[4];
  __shared__ int ptot_sh;
  __shared__ int stage[STAGE_N];
  int b = blockIdx.x, tid = threadIdx.x;
  int lane = tid & 63, wv = tid >> 6;
  int ecnt = min(bcnt[b * 16], BCAP);
  int node0 = b * NPB;
  int nn = min(NPB, n - node0);
  for (int i = tid; i < NPB; i += 256) ncnt[i] = 0;
  for (int i = tid; i < STAGE_N; i += 256) stage[i] = 0;   // zero pads
  __syncthreads();
  const uint4* bq = (const uint4*)(binned + (size_t)b * BCAP);  // BCAP%4==0
  int nv4 = ecnt >> 2;
  for (int i = tid; i < nv4; i += 256) {
    uint4 q = bq[i];
    atomicAdd(&ncnt[q.x >> 24], 1);
    atomicAdd(&ncnt[q.y >> 24], 1);
    atomicAdd(&ncnt[q.z >> 24], 1);
    atomicAdd(&ncnt[q.w >> 24], 1);
  }
  for (int i = (nv4 << 2) + tid; i < ecnt; i += 256)
    atomicAdd(&ncnt[binned[(size_t)b * BCAP + i] >> 24], 1);
  __syncthreads();
  // exclusive scan over 4-padded counts: wave shfl scan + cross-wave fixup
  int v = (tid < nn) ? ((ncnt[tid] + 3) & ~3) : 0;
  int x = v;
  #pragma unroll
  for (int o = 1; o <= 32; o <<= 1) { int y = __shfl_up(x, o); if (lane >= o) x += y; }
  if (lane == 63) wsum[wv] = x;
  __syncthreads();
  int add = 0;
  for (int w = 0; w < wv; w++) add += wsum[w];
  int incl = x + add;
  if (tid < nn) {
    int noff = incl - v;
    cur[tid] = noff;
    offs[node0 + tid] = b * SSTRIDE + noff;
    ndeg[node0 + tid] = ncnt[tid];
    if (tid == nn - 1) ptot_sh = incl;
  }
  __syncthreads();
  // sort pass (uint4)
  for (int i = tid; i < nv4; i += 256) {
    uint4 q = bq[i];
    int p0 = atomicAdd(&cur[q.x >> 24], 1); stage[p0] = (int)(q.x & 0xFFFFFFu);
    int p1 = atomicAdd(&cur[q.y >> 24], 1); stage[p1] = (int)(q.y & 0xFFFFFFu);
    int p2 = atomicAdd(&cur[q.z >> 24], 1); stage[p2] = (int)(q.z & 0xFFFFFFu);
    int p3 = atomicAdd(&cur[q.w >> 24], 1); stage[p3] = (int)(q.w & 0xFFFFFFu);
  }
  for (int i = (nv4 << 2) + tid; i < ecnt; i += 256) {
    unsigned int q = binned[(size_t)b * BCAP + i];
    int p = atomicAdd(&cur[q >> 24], 1);
    stage[p] = (int)(q & 0xFFFFFFu);
  }
  __syncthreads();
  int ptot = ptot_sh;
  int* dst = ssrc + (size_t)b * SSTRIDE;
  for (int i = tid; i < ptot; i += 256) dst[i] = stage[i];
}

// ---------------- per-node GAT aggregation (self-loop in-register, clamped uint4 batch) ----------------
__device__ __forceinline__ void agg_node(int node, int n, const int* __restrict__ offs,
                                         const int* __restrict__ ndeg,
                                         const int* __restrict__ ssrc,
                                         const uint4* __restrict__ hg4,
                                         const float* __restrict__ als,
                                         const float* __restrict__ ald,
                                         float4 bl0, float4 bl1, int l8, float r[8]) {
  int cnode = min(node, n - 1);
  int deg = ndeg[cnode];
  int beg = (deg > 0) ? offs[cnode] : 0;   // deg==0 -> zeroed head slack
  float aldv = ald[cnode];

  float ts = als[cnode] + aldv;
  ts = fmaxf(ts, 0.2f * ts);
  float exs = __expf(ts);
  float s = exs;
  uint4 us = hg4[(size_t)cnode * 8 + l8];
  float acc[8];
  acc[0] = exs * __uint_as_float(us.x << 16);
  acc[1] = exs * __uint_as_float(us.x & 0xffff0000u);
  acc[2] = exs * __uint_as_float(us.y << 16);
  acc[3] = exs * __uint_as_float(us.y & 0xffff0000u);
  acc[4] = exs * __uint_as_float(us.z << 16);
  acc[5] = exs * __uint_as_float(us.z & 0xffff0000u);
  acc[6] = exs * __uint_as_float(us.w << 16);
  acc[7] = exs * __uint_as_float(us.w & 0xffff0000u);

  int dm = deg;
  #pragma unroll
  for (int o = 8; o <= 32; o <<= 1) dm = max(dm, __shfl_xor(dm, o));
  int dm4 = (dm + 3) >> 2;
  int own4 = max((deg + 3) >> 2, 1);       // own padded uint4 count (>=1)

  const uint4* s4p = (const uint4*)(ssrc + beg);   // 16B-aligned by construction
  for (int j4 = 0; j4 < dm4; j4++) {
    uint4 s4 = s4p[min(j4, own4 - 1)];     // clamp: stay inside own segment
    int jb = j4 << 2;                      // mask uses UNCLAMPED index -> re-reads contribute 0
    #pragma unroll
    for (int u = 0; u < 4; u++) {
      int src = (u == 0) ? (int)s4.x : (u == 1) ? (int)s4.y : (u == 2) ? (int)s4.z : (int)s4.w;
      float t = als[src] + aldv;
      t = fmaxf(t, 0.2f * t);                   // leaky_relu 0.2
      float ex = (jb + u < deg) ? __expf(t) : 0.f;
      s += ex;
      uint4 uu = hg4[(size_t)src * 8 + l8];
      acc[0] = fmaf(ex, __uint_as_float(uu.x << 16), acc[0]);
      acc[1] = fmaf(ex, __uint_as_float(uu.x & 0xffff0000u), acc[1]);
      acc[2] = fmaf(ex, __uint_as_float(uu.y << 16), acc[2]);
      acc[3] = fmaf(ex, __uint_as_float(uu.y & 0xffff0000u), acc[3]);
      acc[4] = fmaf(ex, __uint_as_float(uu.z << 16), acc[4]);
      acc[5] = fmaf(ex, __uint_as_float(uu.z & 0xffff0000u), acc[5]);
      acc[6] = fmaf(ex, __uint_as_float(uu.w << 16), acc[6]);
      acc[7] = fmaf(ex, __uint_as_float(uu.w & 0xffff0000u), acc[7]);
    }
  }

  float iv = 1.f / (s + 1e-16f);
  r[0] = fmaxf(fmaf(acc[0], iv, bl0.x), 0.f);
  r[1] = fmaxf(fmaf(acc[1], iv, bl0.y), 0.f);
  r[2] = fmaxf(fmaf(acc[2], iv, bl0.z), 0.f);
  r[3] = fmaxf(fmaf(acc[3], iv, bl0.w), 0.f);
  r[4] = fmaxf(fmaf(acc[4], iv, bl1.x), 0.f);
  r[5] = fmaxf(fmaf(acc[5], iv, bl1.y), 0.f);
  r[6] = fmaxf(fmaf(acc[6], iv, bl1.z), 0.f);
  r[7] = fmaxf(fmaf(acc[7], iv, bl1.w), 0.f);
}

// ---------------- fused: layer-1 aggregation -> LDS tile -> layer-2 GEMM ----------------
__global__ __launch_bounds__(256) void k_spmm_g2(const int* __restrict__ offs, const int* __restrict__ ndeg,
                                                 const int* __restrict__ ssrc,
                                                 const unsigned short* __restrict__ hgb,
                                                 const float* __restrict__ als, const float* __restrict__ ald,
                                                 const float* __restrict__ bias, const uint4* __restrict__ wf2,
                                                 const float* __restrict__ avs, const float* __restrict__ avd,
                                                 unsigned short* __restrict__ hgb2, float* __restrict__ als2,
                                                 float* __restrict__ ald2, int n) {
  __shared__ __align__(16) unsigned short hsh[64][72];  // +8 pad: balanced banks for b128 W/R
  int tid = threadIdx.x, lane = tid & 63, wv = tid >> 6;
  int g8 = lane >> 3, l8 = lane & 7;
  const uint4* hg4 = (const uint4*)hgb;
  float4 bl0 = ((const float4*)bias)[l8 * 2];
  float4 bl1 = ((const float4*)bias)[l8 * 2 + 1];

  for (int p = 0; p < 2; p++) {
    int row = p * 32 + wv * 8 + g8;
    int node = blockIdx.x * 64 + row;
    float r[8];
    agg_node(node, n, offs, ndeg, ssrc, hg4, als, ald, bl0, bl1, l8, r);
    unsigned short pk[8];
    #pragma unroll
    for (int k = 0; k < 8; k++) pk[k] = f2bf(r[k]);
    *(uint4*)&hsh[row][l8 * 8] = *(const uint4*)pk;
  }
  __syncthreads();

  // layer-2 GEMM on the 64x64 LDS tile
  int l15 = lane & 15, quad = lane >> 4;
  bf16x8 bfr[4][2];
  #pragma unroll
  for (int cb = 0; cb < 8; cb++) {
    uint4 u = wf2[cb * 64 + lane];
    bfr[cb >> 1][cb & 1] = *(const bf16x8*)&u;
  }
  float as_l[4], ad_l[4];
  #pragma unroll
  for (int c = 0; c < 4; c++) { as_l[c] = avs[c * 16 + l15]; ad_l[c] = avd[c * 16 + l15]; }

  int r0 = wv << 4;
  uint4 u0 = *(const uint4*)&hsh[r0 + l15][quad * 8];
  uint4 u1 = *(const uint4*)&hsh[r0 + l15][quad * 8 + 32];
  bf16x8 a0 = *(const bf16x8*)&u0;
  bf16x8 a1 = *(const bf16x8*)&u1;
  f32x4 cfr[4];
  #pragma unroll
  for (int c = 0; c < 4; c++) {
    cfr[c] = (f32x4){0.f, 0.f, 0.f, 0.f};
    cfr[c] = __builtin_amdgcn_mfma_f32_16x16x32_bf16(a0, bfr[c][0], cfr[c], 0, 0, 0);
    cfr[c] = __builtin_amdgcn_mfma_f32_16x16x32_bf16(a1, bfr[c][1], cfr[c], 0, 0, 0);
  }
  #pragma unroll
  for (int i = 0; i < 4; i++) {
    int row = blockIdx.x * 64 + r0 + quad * 4 + i;
    #pragma unroll
    for (int c = 0; c < 4; c++) hgb2[(size_t)row * F + c * 16 + l15] = f2bf(cfr[c][i]);
    float ps = cfr[0][i] * as_l[0] + cfr[1][i] * as_l[1] + cfr[2][i] * as_l[2] + cfr[3][i] * as_l[3];
    float pd = cfr[0][i] * ad_l[0] + cfr[1][i] * ad_l[1] + cfr[2][i] * ad_l[2] + cfr[3][i] * ad_l[3];
    #pragma unroll
    for (int o = 1; o <= 8; o <<= 1) { ps += __shfl_xor(ps, o); pd += __shfl_xor(pd, o); }
    if (l15 == 0) { als2[row] = ps; ald2[row] = pd; }
  }
}

// ---------------- layer-2 aggregation + fused readout ----------------
__global__ __launch_bounds__(256) void k_spmm_out(const int* __restrict__ offs, const int* __restrict__ ndeg,
                                                  const int* __restrict__ ssrc,
                                                  const unsigned short* __restrict__ hgb,
                                                  const float* __restrict__ als, const float* __restrict__ ald,
                                                  const float* __restrict__ bias, const float* __restrict__ Wout,
                                                  float* __restrict__ out, int n) {
  int tid = threadIdx.x, lane = tid & 63, wv = tid >> 6;
  int g8 = lane >> 3, l8 = lane & 7;
  const uint4* hg4 = (const uint4*)hgb;
  float4 bl0 = ((const float4*)bias)[l8 * 2];
  float4 bl1 = ((const float4*)bias)[l8 * 2 + 1];

  __shared__ float gsl[3];
  if (tid < 3) gsl[tid] = 0.f;

  int node = (blockIdx.x * 4 + wv) * 8 + g8;
  bool nodeok = node < n;
  int cnode = min(node, n - 1);
  float r[8];
  agg_node(node, n, offs, ndeg, ssrc, hg4, als, ald, bl0, bl1, l8, r);

  int node0 = blockIdx.x * 32;
  int grp0 = node0 / 20;
  int grp = cnode / 20, slot = cnode - grp * 20;
  const float* wr = Wout + slot * F + l8 * 8;
  float dot = 0.f;
  #pragma unroll
  for (int k = 0; k < 8; k++) dot = fmaf(r[k], wr[k], dot);
  #pragma unroll
  for (int o = 1; o <= 4; o <<= 1) dot += __shfl_xor(dot, o);  // within subgroup
  __syncthreads();
  if (nodeok && l8 == 0) atomicAdd(&gsl[grp - grp0], dot);
  __syncthreads();
  if (tid < 3) {
    float v = gsl[tid];
    if (v != 0.f) atomicAdd(out + grp0 + tid, v);
  }
}

// ---------------- launch ----------------
extern "C" void kernel_launch(void* const* d_in, const int* in_sizes, int n_in,
                              void* d_out, int out_size, void* d_ws, size_t ws_size,
                              hipStream_t stream) {
  const float* x   = (const float*)d_in[0];
  const int*   ei  = (const int*)d_in[1];
  const float* W1  = (const float*)d_in[2];
  const float* as1 = (const float*)d_in[3];
  const float* ad1 = (const float*)d_in[4];
  const float* b1  = (const float*)d_in[5];
  const float* W2  = (const float*)d_in[6];
  const float* as2 = (const float*)d_in[7];
  const float* ad2 = (const float*)d_in[8];
  const float* b2  = (const float*)d_in[9];
  const float* Wo  = (const float*)d_in[10];
  const float* bo  = (const float*)d_in[11];
  float* out = (float*)d_out;

  const int N = in_sizes[0] / F;
  const int E = in_sizes[1] / 2;
  const int* esrc = ei;
  const int* edst = ei + E;

  size_t off = 0;
  auto alloc = [&](size_t bytes) -> void* {
    void* p = (char*)d_ws + off;
    off += (bytes + 255) & ~(size_t)255;
    return p;
  };
  unsigned short* hgb  = (unsigned short*)alloc((size_t)N * F * 2);  // layer-1 h (bf16)
  unsigned short* hgb2 = (unsigned short*)alloc((size_t)N * F * 2);  // layer-2 h (bf16); binned aliases
  float* als  = (float*)alloc((size_t)N * 4);
  float* ald  = (float*)alloc((size_t)N * 4);
  float* als2 = (float*)alloc((size_t)N * 4);
  float* ald2 = (float*)alloc((size_t)N * 4);
  int* offs   = (int*)alloc((size_t)(N + 1) * 4);
  int* ndeg   = (int*)alloc((size_t)N * 4);
  int* bcnt   = (int*)alloc((size_t)1024 * 16 * 4);  // per-bucket counters, 64B-padded
  int* ssrc   = (int*)alloc(((size_t)1024 * SSTRIDE) * 4);  // fixed-stride padded CSR
  uint4* wf   = (uint4*)alloc(16384);                // packed W frags: 2 layers x 512 uint4
  (void)ws_size; (void)n_in; (void)out_size;

  // binned (14.7MB) aliases hgb2 (21MB): binned written by scatter_gemm1, fully consumed by
  // bucket_csr; hgb2 first written by the later k_spmm_g2. Same-stream ordering guarantees safety.
  unsigned int* binned = (unsigned int*)hgb2;

  const int NG = N / 20;
  const int NB = (N + NPB - 1) / NPB;                // 1024
  const int S = 256;                                 // scatter blocks
  const int CH = (((E + S - 1) / S) + 3) & ~3;       // chunk, multiple of 4 for int4 loads

  // W pack + counter zero + out init + ssrc head slack
  k_prep<<<2, 256, 0, stream>>>(W1, W2, wf, bcnt, NB, out, bo, NG, ssrc);
  // fused: bucketed scatter (S blocks) + layer-1 GEMM (N/64 blocks)
  k_scatter_gemm1<<<S + (N >> 6), 256, 0, stream>>>(esrc, edst, bcnt, binned, E, CH, S,
                                                    x, wf, as1, ad1, hgb, als, ald, N);
  // per-bucket CSR build (fixed-stride regions, 4-padded segments)
  k_bucket_csr<<<NB, 256, 0, stream>>>(binned, bcnt, ssrc, offs, ndeg, N);
  // fused: layer-1 aggregation -> LDS -> layer-2 GEMM
  k_spmm_g2<<<(N >> 6), 256, 0, stream>>>(offs, ndeg, ssrc, hgb, als, ald, b1, wf + 512, as2, ad2,
                                          hgb2, als2, ald2, N);
  // layer-2 aggregation + fused readout
  k_spmm_out<<<(N >> 5), 256, 0, stream>>>(offs, ndeg, ssrc, hgb2, als2, ald2, b2, Wo, out, N);
}

// Round 8
// 274.900 us; speedup vs baseline: 1.0736x; 1.0736x over previous
//
#include <hip/hip_runtime.h>
#include <math.h>

#define F 64
#define NPB 160        // nodes per bucket
#define BCAP 3584      // per-bucket capacity in binned (mean 2560, +20 sigma)

typedef __attribute__((ext_vector_type(8))) short bf16x8;
typedef __attribute__((ext_vector_type(4))) float f32x4;

__device__ inline unsigned short f2bf(float f) {
  unsigned int u = __float_as_uint(f);
  u += 0x7fffu + ((u >> 16) & 1u);   // round-to-nearest-even
  return (unsigned short)(u >> 16);
}

// ---------------- prep: W fragment pack (block 0) + bcnt zero + out init ----------------
__global__ __launch_bounds__(256) void k_prep(const float* __restrict__ W1, const float* __restrict__ W2,
                                              uint4* __restrict__ wf, int* __restrict__ bcnt, int nb,
                                              float* __restrict__ out, const float* __restrict__ bo, int ng,
                                              int* __restrict__ ssrc, int e) {
  int tid = threadIdx.x;
  if (blockIdx.x == 0) {
    // pack W1/W2 into MFMA B-fragment layout: wf[layer*512 + (c*2+kk)*64 + lane] = 8 bf16 (j=0..7)
    for (int i = tid; i < 1024; i += 256) {
      int layer = i >> 9, rem = i & 511;
      int cb = rem >> 6, lane = rem & 63;
      int c = cb >> 1, kk = cb & 1;
      int l15 = lane & 15, quad = lane >> 4;
      const float* W = layer ? W2 : W1;
      unsigned short p[8];
      #pragma unroll
      for (int j = 0; j < 8; j++) {
        int kd = kk * 32 + quad * 8 + j;
        p[j] = f2bf(W[kd * F + c * 16 + l15]);
      }
      wf[i] = *(const uint4*)p;
    }
  } else {
    for (int i = tid; i < nb * 16; i += 256) bcnt[i] = 0;  // counters padded to 64B lines
    float b0 = bo[0];
    for (int i = tid; i < ng; i += 256) out[i] = b0;
    if (tid < 64) ssrc[e + tid] = 0;                       // tail slack
  }
}

// ---------------- MFMA GEMM body: fp32 input rows -> bf16 h + als/ald ----------------
__device__ __forceinline__ void gemm_body(const float* __restrict__ in, const uint4* __restrict__ wf,
                                          const float* __restrict__ avs, const float* __restrict__ avd,
                                          unsigned short* __restrict__ hgb, float* __restrict__ als,
                                          float* __restrict__ ald, int n, int bid, int nbl) {
  int tid = threadIdx.x, lane = tid & 63, wv = tid >> 6;
  int l15 = lane & 15, quad = lane >> 4;
  bf16x8 bfr[4][2];
  #pragma unroll
  for (int cb = 0; cb < 8; cb++) {
    uint4 u = wf[cb * 64 + lane];
    bfr[cb >> 1][cb & 1] = *(const bf16x8*)&u;
  }
  float as_l[4], ad_l[4];
  #pragma unroll
  for (int c = 0; c < 4; c++) { as_l[c] = avs[c * 16 + l15]; ad_l[c] = avd[c * 16 + l15]; }

  int nchunks = n >> 6;
  for (int chunk = bid; chunk < nchunks; chunk += nbl) {
    int r0 = (chunk << 6) + (wv << 4);
    bf16x8 a0, a1;
    const float4* xr = (const float4*)(in + (size_t)(r0 + l15) * F + quad * 8);
    float4 xa = xr[0], xb = xr[1];
    float4 xc = xr[8], xd = xr[9];
    a0[0] = (short)f2bf(xa.x); a0[1] = (short)f2bf(xa.y); a0[2] = (short)f2bf(xa.z); a0[3] = (short)f2bf(xa.w);
    a0[4] = (short)f2bf(xb.x); a0[5] = (short)f2bf(xb.y); a0[6] = (short)f2bf(xb.z); a0[7] = (short)f2bf(xb.w);
    a1[0] = (short)f2bf(xc.x); a1[1] = (short)f2bf(xc.y); a1[2] = (short)f2bf(xc.z); a1[3] = (short)f2bf(xc.w);
    a1[4] = (short)f2bf(xd.x); a1[5] = (short)f2bf(xd.y); a1[6] = (short)f2bf(xd.z); a1[7] = (short)f2bf(xd.w);
    f32x4 cfr[4];
    #pragma unroll
    for (int c = 0; c < 4; c++) {
      cfr[c] = (f32x4){0.f, 0.f, 0.f, 0.f};
      cfr[c] = __builtin_amdgcn_mfma_f32_16x16x32_bf16(a0, bfr[c][0], cfr[c], 0, 0, 0);
      cfr[c] = __builtin_amdgcn_mfma_f32_16x16x32_bf16(a1, bfr[c][1], cfr[c], 0, 0, 0);
    }
    #pragma unroll
    for (int i = 0; i < 4; i++) {
      int row = r0 + quad * 4 + i;
      #pragma unroll
      for (int c = 0; c < 4; c++) hgb[(size_t)row * F + c * 16 + l15] = f2bf(cfr[c][i]);
      float ps = cfr[0][i] * as_l[0] + cfr[1][i] * as_l[1] + cfr[2][i] * as_l[2] + cfr[3][i] * as_l[3];
      float pd = cfr[0][i] * ad_l[0] + cfr[1][i] * ad_l[1] + cfr[2][i] * ad_l[2] + cfr[3][i] * ad_l[3];
      #pragma unroll
      for (int o = 1; o <= 8; o <<= 1) { ps += __shfl_xor(ps, o); pd += __shfl_xor(pd, o); }
      if (l15 == 0) { als[row] = ps; ald[row] = pd; }
    }
  }
}

// ---------------- fused: bucketed scatter (blocks < S) + layer-1 GEMM ----------------
__global__ __launch_bounds__(256) void k_scatter_gemm1(const int* __restrict__ esrc, const int* __restrict__ edst,
                                                       int* __restrict__ bcnt, unsigned int* __restrict__ binned,
                                                       int e, int ch, int S,
                                                       const float* __restrict__ x, const uint4* __restrict__ wf,
                                                       const float* __restrict__ avs, const float* __restrict__ avd,
                                                       unsigned short* __restrict__ hgb, float* __restrict__ als,
                                                       float* __restrict__ ald, int n) {
  int k = blockIdx.x, tid = threadIdx.x;
  if (k < S) {
    __shared__ int hist[1024];
    __shared__ int cur[1024];
    for (int i = tid; i < 1024; i += 256) hist[i] = 0;
    __syncthreads();
    int beg = k * ch, end = min(e, beg + ch);
    int len = end - beg;
    if (len <= 0) return;
    int nv = len >> 2;  // beg is 16B-aligned (ch multiple of 4)
    // phase A: histogram
    for (int g = tid; g < nv; g += 256) {
      int4 d4 = *(const int4*)(edst + beg + (g << 2));
      atomicAdd(&hist[d4.x / NPB], 1);
      atomicAdd(&hist[d4.y / NPB], 1);
      atomicAdd(&hist[d4.z / NPB], 1);
      atomicAdd(&hist[d4.w / NPB], 1);
    }
    for (int i = beg + (nv << 2) + tid; i < end; i += 256) atomicAdd(&hist[edst[i] / NPB], 1);
    __syncthreads();
    // phase B: reserve per-bucket runs (global atomics on padded counters)
    for (int b = tid; b < 1024; b += 256) {
      int c = hist[b];
      int base = 0;
      if (c) base = atomicAdd(&bcnt[b * 16], c);
      cur[b] = b * BCAP + base;
    }
    __syncthreads();
    // phase C: place
    for (int g = tid; g < nv; g += 256) {
      int i = beg + (g << 2);
      int4 d4 = *(const int4*)(edst + i);
      int4 s4 = *(const int4*)(esrc + i);
      #pragma unroll
      for (int j = 0; j < 4; j++) {
        int d = (j == 0) ? d4.x : (j == 1) ? d4.y : (j == 2) ? d4.z : d4.w;
        int s = (j == 0) ? s4.x : (j == 1) ? s4.y : (j == 2) ? s4.z : s4.w;
        int b = d / NPB;
        int p = atomicAdd(&cur[b], 1);
        if (p < (b + 1) * BCAP) binned[p] = (unsigned int)s | ((unsigned int)(d - b * NPB) << 24);
      }
    }
    for (int i = beg + (nv << 2) + tid; i < end; i += 256) {
      int d = edst[i];
      int b = d / NPB;
      int p = atomicAdd(&cur[b], 1);
      if (p < (b + 1) * BCAP) binned[p] = (unsigned int)esrc[i] | ((unsigned int)(d - b * NPB) << 24);
    }
    return;
  }
  gemm_body(x, wf, avs, avd, hgb, als, ald, n, k - S, (int)gridDim.x - S);
}

// one block per bucket: prefix obase from bcnt (L2-resident), per-node counting sort via
// LDS stage, emit packed ssrc + offs. Edges only (self-loops handled in-register downstream).
__global__ __launch_bounds__(256) void k_bucket_csr(const unsigned int* __restrict__ binned,
                                                    const int* __restrict__ bcnt,
                                                    int* __restrict__ ssrc, int* __restrict__ offs,
                                                    int n, int nb) {
  __shared__ int ncnt[NPB];
  __shared__ int cur[NPB];
  __shared__ int red[256];
  __shared__ int wsum[4];
  __shared__ int stage[BCAP];
  int b = blockIdx.x, tid = threadIdx.x;
  int lane = tid & 63, wv = tid >> 6;
  // output base: prefix sum over earlier buckets (bcnt is L2-resident)
  int acc = 0;
  for (int j = tid; j < b; j += 256) acc += min(bcnt[j * 16], BCAP);
  red[tid] = acc;
  __syncthreads();
  #pragma unroll
  for (int o = 128; o > 0; o >>= 1) {
    if (tid < o) red[tid] += red[tid + o];
    __syncthreads();
  }
  int outbase = red[0];
  int ecnt = min(bcnt[b * 16], BCAP);
  int node0 = b * NPB;
  int nn = min(NPB, n - node0);
  const uint4* bq = (const uint4*)(binned + (size_t)b * BCAP);  // BCAP%4==0 -> 16B aligned
  int nv4 = ecnt >> 2;
  for (int i = tid; i < NPB; i += 256) ncnt[i] = 0;
  __syncthreads();
  // hist pass (uint4)
  for (int i = tid; i < nv4; i += 256) {
    uint4 q = bq[i];
    atomicAdd(&ncnt[q.x >> 24], 1);
    atomicAdd(&ncnt[q.y >> 24], 1);
    atomicAdd(&ncnt[q.z >> 24], 1);
    atomicAdd(&ncnt[q.w >> 24], 1);
  }
  for (int i = (nv4 << 2) + tid; i < ecnt; i += 256)
    atomicAdd(&ncnt[binned[(size_t)b * BCAP + i] >> 24], 1);
  __syncthreads();
  // exclusive scan over nn node counts: wave shfl scan + cross-wave fixup (2 barriers)
  int v = (tid < nn) ? ncnt[tid] : 0;
  int x = v;
  #pragma unroll
  for (int o = 1; o <= 32; o <<= 1) { int y = __shfl_up(x, o); if (lane >= o) x += y; }
  if (lane == 63) wsum[wv] = x;
  __syncthreads();
  int add = 0;
  for (int w = 0; w < wv; w++) add += wsum[w];
  int incl = x + add;
  if (tid < nn) {
    int noff = incl - v;
    cur[tid] = noff;
    offs[node0 + tid] = outbase + noff;
  }
  __syncthreads();
  // sort pass (uint4)
  for (int i = tid; i < nv4; i += 256) {
    uint4 q = bq[i];
    int p0 = atomicAdd(&cur[q.x >> 24], 1); stage[p0] = (int)(q.x & 0xFFFFFFu);
    int p1 = atomicAdd(&cur[q.y >> 24], 1); stage[p1] = (int)(q.y & 0xFFFFFFu);
    int p2 = atomicAdd(&cur[q.z >> 24], 1); stage[p2] = (int)(q.z & 0xFFFFFFu);
    int p3 = atomicAdd(&cur[q.w >> 24], 1); stage[p3] = (int)(q.w & 0xFFFFFFu);
  }
  for (int i = (nv4 << 2) + tid; i < ecnt; i += 256) {
    unsigned int q = binned[(size_t)b * BCAP + i];
    int p = atomicAdd(&cur[q >> 24], 1);
    stage[p] = (int)(q & 0xFFFFFFu);
  }
  __syncthreads();
  for (int i = tid; i < ecnt; i += 256) ssrc[outbase + i] = stage[i];
  if (b == nb - 1 && tid == 0) offs[n] = outbase + ecnt;
}

// ---------------- per-node GAT aggregation (self-loop in-register) ----------------
// Loop runs exactly deg iterations; divergence is subgroup-uniform (8 lanes share a node),
// so finished subgroups issue NO loads (vs old dm-max + clamped dummy gathers = ~27% waste).
__device__ __forceinline__ void agg_node(int node, int n, const int* __restrict__ offs,
                                         const int* __restrict__ ssrc,
                                         const uint4* __restrict__ hg4,
                                         const float* __restrict__ als,
                                         const float* __restrict__ ald,
                                         float4 bl0, float4 bl1, int l8, float r[8]) {
  int cnode = min(node, n - 1);
  int beg = offs[cnode];
  int deg = offs[cnode + 1] - beg;
  float aldv = ald[cnode];

  float ts = als[cnode] + aldv;
  ts = fmaxf(ts, 0.2f * ts);
  float exs = __expf(ts);
  float s = exs;
  uint4 us = hg4[(size_t)cnode * 8 + l8];
  float acc[8];
  acc[0] = exs * __uint_as_float(us.x << 16);
  acc[1] = exs * __uint_as_float(us.x & 0xffff0000u);
  acc[2] = exs * __uint_as_float(us.y << 16);
  acc[3] = exs * __uint_as_float(us.y & 0xffff0000u);
  acc[4] = exs * __uint_as_float(us.z << 16);
  acc[5] = exs * __uint_as_float(us.z & 0xffff0000u);
  acc[6] = exs * __uint_as_float(us.w << 16);
  acc[7] = exs * __uint_as_float(us.w & 0xffff0000u);

  #pragma unroll 4
  for (int j = 0; j < deg; j++) {
    int src = ssrc[beg + j];
    float t = als[src] + aldv;
    t = fmaxf(t, 0.2f * t);                   // leaky_relu 0.2
    float ex = __expf(t);
    s += ex;
    uint4 u = hg4[(size_t)src * 8 + l8];
    acc[0] = fmaf(ex, __uint_as_float(u.x << 16), acc[0]);
    acc[1] = fmaf(ex, __uint_as_float(u.x & 0xffff0000u), acc[1]);
    acc[2] = fmaf(ex, __uint_as_float(u.y << 16), acc[2]);
    acc[3] = fmaf(ex, __uint_as_float(u.y & 0xffff0000u), acc[3]);
    acc[4] = fmaf(ex, __uint_as_float(u.z << 16), acc[4]);
    acc[5] = fmaf(ex, __uint_as_float(u.z & 0xffff0000u), acc[5]);
    acc[6] = fmaf(ex, __uint_as_float(u.w << 16), acc[6]);
    acc[7] = fmaf(ex, __uint_as_float(u.w & 0xffff0000u), acc[7]);
  }

  float iv = 1.f / (s + 1e-16f);
  r[0] = fmaxf(fmaf(acc[0], iv, bl0.x), 0.f);
  r[1] = fmaxf(fmaf(acc[1], iv, bl0.y), 0.f);
  r[2] = fmaxf(fmaf(acc[2], iv, bl0.z), 0.f);
  r[3] = fmaxf(fmaf(acc[3], iv, bl0.w), 0.f);
  r[4] = fmaxf(fmaf(acc[4], iv, bl1.x), 0.f);
  r[5] = fmaxf(fmaf(acc[5], iv, bl1.y), 0.f);
  r[6] = fmaxf(fmaf(acc[6], iv, bl1.z), 0.f);
  r[7] = fmaxf(fmaf(acc[7], iv, bl1.w), 0.f);
}

// ---------------- fused: layer-1 aggregation -> LDS tile -> layer-2 GEMM ----------------
__global__ __launch_bounds__(256) void k_spmm_g2(const int* __restrict__ offs, const int* __restrict__ ssrc,
                                                 const unsigned short* __restrict__ hgb,
                                                 const float* __restrict__ als, const float* __restrict__ ald,
                                                 const float* __restrict__ bias, const uint4* __restrict__ wf2,
                                                 const float* __restrict__ avs, const float* __restrict__ avd,
                                                 unsigned short* __restrict__ hgb2, float* __restrict__ als2,
                                                 float* __restrict__ ald2, int n) {
  __shared__ __align__(16) unsigned short hsh[64][72];  // +8 pad: balanced banks for b128 W/R
  int tid = threadIdx.x, lane = tid & 63, wv = tid >> 6;
  int g8 = lane >> 3, l8 = lane & 7;
  const uint4* hg4 = (const uint4*)hgb;
  float4 bl0 = ((const float4*)bias)[l8 * 2];
  float4 bl1 = ((const float4*)bias)[l8 * 2 + 1];

  for (int p = 0; p < 2; p++) {
    int row = p * 32 + wv * 8 + g8;
    int node = blockIdx.x * 64 + row;
    float r[8];
    agg_node(node, n, offs, ssrc, hg4, als, ald, bl0, bl1, l8, r);
    unsigned short pk[8];
    #pragma unroll
    for (int k = 0; k < 8; k++) pk[k] = f2bf(r[k]);
    *(uint4*)&hsh[row][l8 * 8] = *(const uint4*)pk;
  }
  __syncthreads();

  // layer-2 GEMM on the 64x64 LDS tile
  int l15 = lane & 15, quad = lane >> 4;
  bf16x8 bfr[4][2];
  #pragma unroll
  for (int cb = 0; cb < 8; cb++) {
    uint4 u = wf2[cb * 64 + lane];
    bfr[cb >> 1][cb & 1] = *(const bf16x8*)&u;
  }
  float as_l[4], ad_l[4];
  #pragma unroll
  for (int c = 0; c < 4; c++) { as_l[c] = avs[c * 16 + l15]; ad_l[c] = avd[c * 16 + l15]; }

  int r0 = wv << 4;
  uint4 u0 = *(const uint4*)&hsh[r0 + l15][quad * 8];
  uint4 u1 = *(const uint4*)&hsh[r0 + l15][quad * 8 + 32];
  bf16x8 a0 = *(const bf16x8*)&u0;
  bf16x8 a1 = *(const bf16x8*)&u1;
  f32x4 cfr[4];
  #pragma unroll
  for (int c = 0; c < 4; c++) {
    cfr[c] = (f32x4){0.f, 0.f, 0.f, 0.f};
    cfr[c] = __builtin_amdgcn_mfma_f32_16x16x32_bf16(a0, bfr[c][0], cfr[c], 0, 0, 0);
    cfr[c] = __builtin_amdgcn_mfma_f32_16x16x32_bf16(a1, bfr[c][1], cfr[c], 0, 0, 0);
  }
  #pragma unroll
  for (int i = 0; i < 4; i++) {
    int row = blockIdx.x * 64 + r0 + quad * 4 + i;
    #pragma unroll
    for (int c = 0; c < 4; c++) hgb2[(size_t)row * F + c * 16 + l15] = f2bf(cfr[c][i]);
    float ps = cfr[0][i] * as_l[0] + cfr[1][i] * as_l[1] + cfr[2][i] * as_l[2] + cfr[3][i] * as_l[3];
    float pd = cfr[0][i] * ad_l[0] + cfr[1][i] * ad_l[1] + cfr[2][i] * ad_l[2] + cfr[3][i] * ad_l[3];
    #pragma unroll
    for (int o = 1; o <= 8; o <<= 1) { ps += __shfl_xor(ps, o); pd += __shfl_xor(pd, o); }
    if (l15 == 0) { als2[row] = ps; ald2[row] = pd; }
  }
}

// ---------------- layer-2 aggregation + fused readout ----------------
__global__ __launch_bounds__(256) void k_spmm_out(const int* __restrict__ offs, const int* __restrict__ ssrc,
                                                  const unsigned short* __restrict__ hgb,
                                                  const float* __restrict__ als, const float* __restrict__ ald,
                                                  const float* __restrict__ bias, const float* __restrict__ Wout,
                                                  float* __restrict__ out, int n) {
  int tid = threadIdx.x, lane = tid & 63, wv = tid >> 6;
  int g8 = lane >> 3, l8 = lane & 7;
  const uint4* hg4 = (const uint4*)hgb;
  float4 bl0 = ((const float4*)bias)[l8 * 2];
  float4 bl1 = ((const float4*)bias)[l8 * 2 + 1];

  __shared__ float gsl[3];
  if (tid < 3) gsl[tid] = 0.f;

  int node = (blockIdx.x * 4 + wv) * 8 + g8;
  bool nodeok = node < n;
  int cnode = min(node, n - 1);
  float r[8];
  agg_node(node, n, offs, ssrc, hg4, als, ald, bl0, bl1, l8, r);

  int node0 = blockIdx.x * 32;
  int grp0 = node0 / 20;
  int grp = cnode / 20, slot = cnode - grp * 20;
  const float* wr = Wout + slot * F + l8 * 8;
  float dot = 0.f;
  #pragma unroll
  for (int k = 0; k < 8; k++) dot = fmaf(r[k], wr[k], dot);
  #pragma unroll
  for (int o = 1; o <= 4; o <<= 1) dot += __shfl_xor(dot, o);  // within subgroup
  __syncthreads();
  if (nodeok && l8 == 0) atomicAdd(&gsl[grp - grp0], dot);
  __syncthreads();
  if (tid < 3) {
    float v = gsl[tid];
    if (v != 0.f) atomicAdd(out + grp0 + tid, v);
  }
}

// ---------------- launch ----------------
extern "C" void kernel_launch(void* const* d_in, const int* in_sizes, int n_in,
                              void* d_out, int out_size, void* d_ws, size_t ws_size,
                              hipStream_t stream) {
  const float* x   = (const float*)d_in[0];
  const int*   ei  = (const int*)d_in[1];
  const float* W1  = (const float*)d_in[2];
  const float* as1 = (const float*)d_in[3];
  const float* ad1 = (const float*)d_in[4];
  const float* b1  = (const float*)d_in[5];
  const float* W2  = (const float*)d_in[6];
  const float* as2 = (const float*)d_in[7];
  const float* ad2 = (const float*)d_in[8];
  const float* b2  = (const float*)d_in[9];
  const float* Wo  = (const float*)d_in[10];
  const float* bo  = (const float*)d_in[11];
  float* out = (float*)d_out;

  const int N = in_sizes[0] / F;
  const int E = in_sizes[1] / 2;
  const int* esrc = ei;
  const int* edst = ei + E;

  size_t off = 0;
  auto alloc = [&](size_t bytes) -> void* {
    void* p = (char*)d_ws + off;
    off += (bytes + 255) & ~(size_t)255;
    return p;
  };
  unsigned short* hgb  = (unsigned short*)alloc((size_t)N * F * 2);  // layer-1 h (bf16)
  unsigned short* hgb2 = (unsigned short*)alloc((size_t)N * F * 2);  // layer-2 h (bf16)
  float* als  = (float*)alloc((size_t)N * 4);
  float* ald  = (float*)alloc((size_t)N * 4);
  float* als2 = (float*)alloc((size_t)N * 4);
  float* ald2 = (float*)alloc((size_t)N * 4);
  int* offs   = (int*)alloc((size_t)(N + 1) * 4);
  int* bcnt   = (int*)alloc((size_t)1024 * 16 * 4);  // per-bucket counters, 64B-padded
  int* ssrc   = (int*)alloc((size_t)(E + 64) * 4);   // CSR src lists (edges only) + slack
  unsigned int* binned = (unsigned int*)alloc((size_t)1024 * BCAP * 4);
  uint4* wf   = (uint4*)alloc(16384);                // packed W frags: 2 layers x 512 uint4
  (void)ws_size; (void)n_in; (void)out_size;

  const int NG = N / 20;
  const int NB = (N + NPB - 1) / NPB;                // 1024
  const int S = 256;                                 // scatter blocks
  const int CH = (((E + S - 1) / S) + 3) & ~3;       // chunk, multiple of 4 for int4 loads

  // W pack + counter zero + out init + ssrc slack
  k_prep<<<2, 256, 0, stream>>>(W1, W2, wf, bcnt, NB, out, bo, NG, ssrc, E);
  // fused: bucketed scatter (S blocks) + layer-1 GEMM (N/64 blocks)
  k_scatter_gemm1<<<S + (N >> 6), 256, 0, stream>>>(esrc, edst, bcnt, binned, E, CH, S,
                                                    x, wf, as1, ad1, hgb, als, ald, N);
  // per-bucket CSR build (obase computed in-kernel from bcnt)
  k_bucket_csr<<<NB, 256, 0, stream>>>(binned, bcnt, ssrc, offs, N, NB);
  // fused: layer-1 aggregation -> LDS -> layer-2 GEMM
  k_spmm_g2<<<(N >> 6), 256, 0, stream>>>(offs, ssrc, hgb, als, ald, b1, wf + 512, as2, ad2,
                                          hgb2, als2, ald2, N);
  // layer-2 aggregation + fused readout
  k_spmm_out<<<(N >> 5), 256, 0, stream>>>(offs, ssrc, hgb2, als2, ald2, b2, Wo, out, N);
}

// Round 9
// 270.495 us; speedup vs baseline: 1.0911x; 1.0163x over previous
//
#include <hip/hip_runtime.h>
#include <math.h>

#define F 64
#define NPB 160        // nodes per bucket
#define BCAP 3584      // per-bucket capacity in binned (mean 2560, +20 sigma)

typedef __attribute__((ext_vector_type(8))) short bf16x8;
typedef __attribute__((ext_vector_type(4))) float f32x4;

__device__ inline unsigned short f2bf(float f) {
  unsigned int u = __float_as_uint(f);
  u += 0x7fffu + ((u >> 16) & 1u);   // round-to-nearest-even
  return (unsigned short)(u >> 16);
}

// ---------------- prep: W fragment pack (block 0) + bcnt zero + out init ----------------
__global__ __launch_bounds__(256) void k_prep(const float* __restrict__ W1, const float* __restrict__ W2,
                                              uint4* __restrict__ wf, int* __restrict__ bcnt, int nb,
                                              float* __restrict__ out, const float* __restrict__ bo, int ng) {
  int tid = threadIdx.x;
  if (blockIdx.x == 0) {
    // pack W1/W2 into MFMA B-fragment layout: wf[layer*512 + (c*2+kk)*64 + lane] = 8 bf16 (j=0..7)
    for (int i = tid; i < 1024; i += 256) {
      int layer = i >> 9, rem = i & 511;
      int cb = rem >> 6, lane = rem & 63;
      int c = cb >> 1, kk = cb & 1;
      int l15 = lane & 15, quad = lane >> 4;
      const float* W = layer ? W2 : W1;
      unsigned short p[8];
      #pragma unroll
      for (int j = 0; j < 8; j++) {
        int kd = kk * 32 + quad * 8 + j;
        p[j] = f2bf(W[kd * F + c * 16 + l15]);
      }
      wf[i] = *(const uint4*)p;
    }
  } else {
    for (int i = tid; i < nb * 16; i += 256) bcnt[i] = 0;  // counters padded to 64B lines
    float b0 = bo[0];
    for (int i = tid; i < ng; i += 256) out[i] = b0;
  }
}

// ---------------- MFMA GEMM body: fp32 input rows -> bf16 h + als/ald ----------------
__device__ __forceinline__ void gemm_body(const float* __restrict__ in, const uint4* __restrict__ wf,
                                          const float* __restrict__ avs, const float* __restrict__ avd,
                                          unsigned short* __restrict__ hgb, float* __restrict__ als,
                                          float* __restrict__ ald, int n, int bid, int nbl) {
  int tid = threadIdx.x, lane = tid & 63, wv = tid >> 6;
  int l15 = lane & 15, quad = lane >> 4;
  bf16x8 bfr[4][2];
  #pragma unroll
  for (int cb = 0; cb < 8; cb++) {
    uint4 u = wf[cb * 64 + lane];
    bfr[cb >> 1][cb & 1] = *(const bf16x8*)&u;
  }
  float as_l[4], ad_l[4];
  #pragma unroll
  for (int c = 0; c < 4; c++) { as_l[c] = avs[c * 16 + l15]; ad_l[c] = avd[c * 16 + l15]; }

  int nchunks = n >> 6;
  for (int chunk = bid; chunk < nchunks; chunk += nbl) {
    int r0 = (chunk << 6) + (wv << 4);
    bf16x8 a0, a1;
    const float4* xr = (const float4*)(in + (size_t)(r0 + l15) * F + quad * 8);
    float4 xa = xr[0], xb = xr[1];
    float4 xc = xr[8], xd = xr[9];
    a0[0] = (short)f2bf(xa.x); a0[1] = (short)f2bf(xa.y); a0[2] = (short)f2bf(xa.z); a0[3] = (short)f2bf(xa.w);
    a0[4] = (short)f2bf(xb.x); a0[5] = (short)f2bf(xb.y); a0[6] = (short)f2bf(xb.z); a0[7] = (short)f2bf(xb.w);
    a1[0] = (short)f2bf(xc.x); a1[1] = (short)f2bf(xc.y); a1[2] = (short)f2bf(xc.z); a1[3] = (short)f2bf(xc.w);
    a1[4] = (short)f2bf(xd.x); a1[5] = (short)f2bf(xd.y); a1[6] = (short)f2bf(xd.z); a1[7] = (short)f2bf(xd.w);
    f32x4 cfr[4];
    #pragma unroll
    for (int c = 0; c < 4; c++) {
      cfr[c] = (f32x4){0.f, 0.f, 0.f, 0.f};
      cfr[c] = __builtin_amdgcn_mfma_f32_16x16x32_bf16(a0, bfr[c][0], cfr[c], 0, 0, 0);
      cfr[c] = __builtin_amdgcn_mfma_f32_16x16x32_bf16(a1, bfr[c][1], cfr[c], 0, 0, 0);
    }
    #pragma unroll
    for (int i = 0; i < 4; i++) {
      int row = r0 + quad * 4 + i;
      #pragma unroll
      for (int c = 0; c < 4; c++) hgb[(size_t)row * F + c * 16 + l15] = f2bf(cfr[c][i]);
      float ps = cfr[0][i] * as_l[0] + cfr[1][i] * as_l[1] + cfr[2][i] * as_l[2] + cfr[3][i] * as_l[3];
      float pd = cfr[0][i] * ad_l[0] + cfr[1][i] * ad_l[1] + cfr[2][i] * ad_l[2] + cfr[3][i] * ad_l[3];
      #pragma unroll
      for (int o = 1; o <= 8; o <<= 1) { ps += __shfl_xor(ps, o); pd += __shfl_xor(pd, o); }
      if (l15 == 0) { als[row] = ps; ald[row] = pd; }
    }
  }
}

// ---------------- fused: bucketed scatter (blocks < S) + layer-1 GEMM ----------------
__global__ __launch_bounds__(256) void k_scatter_gemm1(const int* __restrict__ esrc, const int* __restrict__ edst,
                                                       int* __restrict__ bcnt, unsigned int* __restrict__ binned,
                                                       int e, int ch, int S,
                                                       const float* __restrict__ x, const uint4* __restrict__ wf,
                                                       const float* __restrict__ avs, const float* __restrict__ avd,
                                                       unsigned short* __restrict__ hgb, float* __restrict__ als,
                                                       float* __restrict__ ald, int n) {
  int k = blockIdx.x, tid = threadIdx.x;
  if (k < S) {
    __shared__ int hist[1024];
    __shared__ int cur[1024];
    for (int i = tid; i < 1024; i += 256) hist[i] = 0;
    __syncthreads();
    int beg = k * ch, end = min(e, beg + ch);
    int len = end - beg;
    if (len <= 0) return;
    int nv = len >> 2;  // beg is 16B-aligned (ch multiple of 4)
    // phase A: histogram
    for (int g = tid; g < nv; g += 256) {
      int4 d4 = *(const int4*)(edst + beg + (g << 2));
      atomicAdd(&hist[d4.x / NPB], 1);
      atomicAdd(&hist[d4.y / NPB], 1);
      atomicAdd(&hist[d4.z / NPB], 1);
      atomicAdd(&hist[d4.w / NPB], 1);
    }
    for (int i = beg + (nv << 2) + tid; i < end; i += 256) atomicAdd(&hist[edst[i] / NPB], 1);
    __syncthreads();
    // phase B: reserve per-bucket runs (global atomics on padded counters)
    for (int b = tid; b < 1024; b += 256) {
      int c = hist[b];
      int base = 0;
      if (c) base = atomicAdd(&bcnt[b * 16], c);
      cur[b] = b * BCAP + base;
    }
    __syncthreads();
    // phase C: place
    for (int g = tid; g < nv; g += 256) {
      int i = beg + (g << 2);
      int4 d4 = *(const int4*)(edst + i);
      int4 s4 = *(const int4*)(esrc + i);
      #pragma unroll
      for (int j = 0; j < 4; j++) {
        int d = (j == 0) ? d4.x : (j == 1) ? d4.y : (j == 2) ? d4.z : d4.w;
        int s = (j == 0) ? s4.x : (j == 1) ? s4.y : (j == 2) ? s4.z : s4.w;
        int b = d / NPB;
        int p = atomicAdd(&cur[b], 1);
        if (p < (b + 1) * BCAP) binned[p] = (unsigned int)s | ((unsigned int)(d - b * NPB) << 24);
      }
    }
    for (int i = beg + (nv << 2) + tid; i < end; i += 256) {
      int d = edst[i];
      int b = d / NPB;
      int p = atomicAdd(&cur[b], 1);
      if (p < (b + 1) * BCAP) binned[p] = (unsigned int)esrc[i] | ((unsigned int)(d - b * NPB) << 24);
    }
    return;
  }
  gemm_body(x, wf, avs, avd, hgb, als, ald, n, k - S, (int)gridDim.x - S);
}

// ---------------- fused: per-bucket CSR build + layer-1 aggregation + layer-2 GEMM ----------------
// One block per 160-node bucket. Phases: prefix outbase from bcnt -> LDS counting-sort of the
// bucket's binned run into stage[] (ssrc/offs persisted for spmm_out as a by-product) ->
// aggregate 160 nodes with edge ids from LDS -> layer-2 GEMM on 10 x 16-row strips.
__global__ __launch_bounds__(256) void k_csr_g2(const unsigned int* __restrict__ binned,
                                                const int* __restrict__ bcnt,
                                                int* __restrict__ ssrc, int* __restrict__ offs,
                                                const unsigned short* __restrict__ hgb,
                                                const float* __restrict__ als, const float* __restrict__ ald,
                                                const float* __restrict__ bias, const uint4* __restrict__ wf2,
                                                const float* __restrict__ avs, const float* __restrict__ avd,
                                                unsigned short* __restrict__ hgb2, float* __restrict__ als2,
                                                float* __restrict__ ald2, int n, int nb) {
  __shared__ int ncnt[NPB];
  __shared__ int noff[NPB];
  __shared__ int cur[NPB];
  __shared__ int wsum[4];
  __shared__ int stage[BCAP];
  __shared__ __align__(16) unsigned short hsh[NPB][72];  // stride 144B: 16B-aligned rows, 2-way banks
  int b = blockIdx.x, tid = threadIdx.x;
  int lane = tid & 63, wv = tid >> 6;
  int* red = stage;  // alias: red phase finishes before stage is written (barriers intervene)

  // output base: prefix sum over earlier buckets (bcnt is L2-resident)
  int acc = 0;
  for (int j = tid; j < b; j += 256) acc += min(bcnt[j * 16], BCAP);
  red[tid] = acc;
  __syncthreads();
  #pragma unroll
  for (int o = 128; o > 0; o >>= 1) {
    if (tid < o) red[tid] += red[tid + o];
    __syncthreads();
  }
  int outbase = red[0];
  int ecnt = min(bcnt[b * 16], BCAP);
  int node0 = b * NPB;
  int nn = min(NPB, n - node0);
  const uint4* bq = (const uint4*)(binned + (size_t)b * BCAP);  // BCAP%4==0 -> 16B aligned
  int nv4 = ecnt >> 2;
  for (int i = tid; i < NPB; i += 256) ncnt[i] = 0;
  __syncthreads();
  // hist pass (uint4)
  for (int i = tid; i < nv4; i += 256) {
    uint4 q = bq[i];
    atomicAdd(&ncnt[q.x >> 24], 1);
    atomicAdd(&ncnt[q.y >> 24], 1);
    atomicAdd(&ncnt[q.z >> 24], 1);
    atomicAdd(&ncnt[q.w >> 24], 1);
  }
  for (int i = (nv4 << 2) + tid; i < ecnt; i += 256)
    atomicAdd(&ncnt[binned[(size_t)b * BCAP + i] >> 24], 1);
  __syncthreads();
  // exclusive scan over nn node counts: wave shfl scan + cross-wave fixup
  int v = (tid < nn) ? ncnt[tid] : 0;
  int x = v;
  #pragma unroll
  for (int o = 1; o <= 32; o <<= 1) { int y = __shfl_up(x, o); if (lane >= o) x += y; }
  if (lane == 63) wsum[wv] = x;
  __syncthreads();   // also fences the red->stage alias handoff
  int add = 0;
  for (int w = 0; w < wv; w++) add += wsum[w];
  int incl = x + add;
  if (tid < nn) {
    int nf = incl - v;
    noff[tid] = nf;
    cur[tid] = nf;
    offs[node0 + tid] = outbase + nf;
  }
  __syncthreads();
  // sort pass (uint4) -> stage
  for (int i = tid; i < nv4; i += 256) {
    uint4 q = bq[i];
    int p0 = atomicAdd(&cur[q.x >> 24], 1); stage[p0] = (int)(q.x & 0xFFFFFFu);
    int p1 = atomicAdd(&cur[q.y >> 24], 1); stage[p1] = (int)(q.y & 0xFFFFFFu);
    int p2 = atomicAdd(&cur[q.z >> 24], 1); stage[p2] = (int)(q.z & 0xFFFFFFu);
    int p3 = atomicAdd(&cur[q.w >> 24], 1); stage[p3] = (int)(q.w & 0xFFFFFFu);
  }
  for (int i = (nv4 << 2) + tid; i < ecnt; i += 256) {
    unsigned int q = binned[(size_t)b * BCAP + i];
    int p = atomicAdd(&cur[q >> 24], 1);
    stage[p] = (int)(q & 0xFFFFFFu);
  }
  __syncthreads();
  // persist CSR for spmm_out (coalesced; overlaps with agg below across blocks)
  for (int i = tid; i < ecnt; i += 256) ssrc[outbase + i] = stage[i];
  if (b == nb - 1 && tid == 0) offs[n] = outbase + ecnt;

  // ---- layer-1 aggregation for this bucket's nodes, edge ids from LDS ----
  int g8 = lane >> 3, l8 = lane & 7;
  const uint4* hg4 = (const uint4*)hgb;
  float4 bl0 = ((const float4*)bias)[l8 * 2];
  float4 bl1 = ((const float4*)bias)[l8 * 2 + 1];

  for (int p = 0; p < 5; p++) {
    int row = p * 32 + wv * 8 + g8;       // 0..159
    int node = node0 + row;
    bool rowok = row < nn;
    int cnode = min(node, n - 1);
    int deg = rowok ? ncnt[row] : 0;
    int lbeg = rowok ? noff[row] : 0;
    float aldv = ald[cnode];

    // self-loop term
    float ts = als[cnode] + aldv;
    ts = fmaxf(ts, 0.2f * ts);
    float exs = __expf(ts);
    float s = exs;
    uint4 us = hg4[(size_t)cnode * 8 + l8];
    float acc8[8];
    acc8[0] = exs * __uint_as_float(us.x << 16);
    acc8[1] = exs * __uint_as_float(us.x & 0xffff0000u);
    acc8[2] = exs * __uint_as_float(us.y << 16);
    acc8[3] = exs * __uint_as_float(us.y & 0xffff0000u);
    acc8[4] = exs * __uint_as_float(us.z << 16);
    acc8[5] = exs * __uint_as_float(us.z & 0xffff0000u);
    acc8[6] = exs * __uint_as_float(us.w << 16);
    acc8[7] = exs * __uint_as_float(us.w & 0xffff0000u);

    #pragma unroll 4
    for (int j = 0; j < deg; j++) {
      int src = stage[lbeg + j];
      float t = als[src] + aldv;
      t = fmaxf(t, 0.2f * t);               // leaky_relu 0.2
      float ex = __expf(t);
      s += ex;
      uint4 u = hg4[(size_t)src * 8 + l8];
      acc8[0] = fmaf(ex, __uint_as_float(u.x << 16), acc8[0]);
      acc8[1] = fmaf(ex, __uint_as_float(u.x & 0xffff0000u), acc8[1]);
      acc8[2] = fmaf(ex, __uint_as_float(u.y << 16), acc8[2]);
      acc8[3] = fmaf(ex, __uint_as_float(u.y & 0xffff0000u), acc8[3]);
      acc8[4] = fmaf(ex, __uint_as_float(u.z << 16), acc8[4]);
      acc8[5] = fmaf(ex, __uint_as_float(u.z & 0xffff0000u), acc8[5]);
      acc8[6] = fmaf(ex, __uint_as_float(u.w << 16), acc8[6]);
      acc8[7] = fmaf(ex, __uint_as_float(u.w & 0xffff0000u), acc8[7]);
    }

    float iv = 1.f / (s + 1e-16f);
    float r[8];
    r[0] = fmaxf(fmaf(acc8[0], iv, bl0.x), 0.f);
    r[1] = fmaxf(fmaf(acc8[1], iv, bl0.y), 0.f);
    r[2] = fmaxf(fmaf(acc8[2], iv, bl0.z), 0.f);
    r[3] = fmaxf(fmaf(acc8[3], iv, bl0.w), 0.f);
    r[4] = fmaxf(fmaf(acc8[4], iv, bl1.x), 0.f);
    r[5] = fmaxf(fmaf(acc8[5], iv, bl1.y), 0.f);
    r[6] = fmaxf(fmaf(acc8[6], iv, bl1.z), 0.f);
    r[7] = fmaxf(fmaf(acc8[7], iv, bl1.w), 0.f);
    unsigned short pk[8];
    #pragma unroll
    for (int kk = 0; kk < 8; kk++) pk[kk] = f2bf(r[kk]);
    *(uint4*)&hsh[row][l8 * 8] = *(const uint4*)pk;
  }
  __syncthreads();

  // ---- layer-2 GEMM on 10 strips of 16 rows ----
  int l15 = lane & 15, quad = lane >> 4;
  bf16x8 bfr[4][2];
  #pragma unroll
  for (int cb = 0; cb < 8; cb++) {
    uint4 u = wf2[cb * 64 + lane];
    bfr[cb >> 1][cb & 1] = *(const bf16x8*)&u;
  }
  float as_l[4], ad_l[4];
  #pragma unroll
  for (int c = 0; c < 4; c++) { as_l[c] = avs[c * 16 + l15]; ad_l[c] = avd[c * 16 + l15]; }

  #pragma unroll
  for (int t = 0; t < 3; t++) {
    int strip = t * 4 + wv;
    if (strip < 10) {
      int r0 = strip << 4;
      uint4 u0 = *(const uint4*)&hsh[r0 + l15][quad * 8];
      uint4 u1 = *(const uint4*)&hsh[r0 + l15][quad * 8 + 32];
      bf16x8 a0 = *(const bf16x8*)&u0;
      bf16x8 a1 = *(const bf16x8*)&u1;
      f32x4 cfr[4];
      #pragma unroll
      for (int c = 0; c < 4; c++) {
        cfr[c] = (f32x4){0.f, 0.f, 0.f, 0.f};
        cfr[c] = __builtin_amdgcn_mfma_f32_16x16x32_bf16(a0, bfr[c][0], cfr[c], 0, 0, 0);
        cfr[c] = __builtin_amdgcn_mfma_f32_16x16x32_bf16(a1, bfr[c][1], cfr[c], 0, 0, 0);
      }
      #pragma unroll
      for (int i = 0; i < 4; i++) {
        int row = node0 + r0 + quad * 4 + i;
        if (row < n) {
          #pragma unroll
          for (int c = 0; c < 4; c++) hgb2[(size_t)row * F + c * 16 + l15] = f2bf(cfr[c][i]);
        }
        float ps = cfr[0][i] * as_l[0] + cfr[1][i] * as_l[1] + cfr[2][i] * as_l[2] + cfr[3][i] * as_l[3];
        float pd = cfr[0][i] * ad_l[0] + cfr[1][i] * ad_l[1] + cfr[2][i] * ad_l[2] + cfr[3][i] * ad_l[3];
        #pragma unroll
        for (int o = 1; o <= 8; o <<= 1) { ps += __shfl_xor(ps, o); pd += __shfl_xor(pd, o); }
        if (l15 == 0 && row < n) { als2[row] = ps; ald2[row] = pd; }
      }
    }
  }
}

// ---------------- per-node GAT aggregation from global CSR (self-loop in-register) ----------------
__device__ __forceinline__ void agg_node(int node, int n, const int* __restrict__ offs,
                                         const int* __restrict__ ssrc,
                                         const uint4* __restrict__ hg4,
                                         const float* __restrict__ als,
                                         const float* __restrict__ ald,
                                         float4 bl0, float4 bl1, int l8, float r[8]) {
  int cnode = min(node, n - 1);
  int beg = offs[cnode];
  int deg = offs[cnode + 1] - beg;
  float aldv = ald[cnode];

  float ts = als[cnode] + aldv;
  ts = fmaxf(ts, 0.2f * ts);
  float exs = __expf(ts);
  float s = exs;
  uint4 us = hg4[(size_t)cnode * 8 + l8];
  float acc[8];
  acc[0] = exs * __uint_as_float(us.x << 16);
  acc[1] = exs * __uint_as_float(us.x & 0xffff0000u);
  acc[2] = exs * __uint_as_float(us.y << 16);
  acc[3] = exs * __uint_as_float(us.y & 0xffff0000u);
  acc[4] = exs * __uint_as_float(us.z << 16);
  acc[5] = exs * __uint_as_float(us.z & 0xffff0000u);
  acc[6] = exs * __uint_as_float(us.w << 16);
  acc[7] = exs * __uint_as_float(us.w & 0xffff0000u);

  #pragma unroll 4
  for (int j = 0; j < deg; j++) {
    int src = ssrc[beg + j];
    float t = als[src] + aldv;
    t = fmaxf(t, 0.2f * t);                   // leaky_relu 0.2
    float ex = __expf(t);
    s += ex;
    uint4 u = hg4[(size_t)src * 8 + l8];
    acc[0] = fmaf(ex, __uint_as_float(u.x << 16), acc[0]);
    acc[1] = fmaf(ex, __uint_as_float(u.x & 0xffff0000u), acc[1]);
    acc[2] = fmaf(ex, __uint_as_float(u.y << 16), acc[2]);
    acc[3] = fmaf(ex, __uint_as_float(u.y & 0xffff0000u), acc[3]);
    acc[4] = fmaf(ex, __uint_as_float(u.z << 16), acc[4]);
    acc[5] = fmaf(ex, __uint_as_float(u.z & 0xffff0000u), acc[5]);
    acc[6] = fmaf(ex, __uint_as_float(u.w << 16), acc[6]);
    acc[7] = fmaf(ex, __uint_as_float(u.w & 0xffff0000u), acc[7]);
  }

  float iv = 1.f / (s + 1e-16f);
  r[0] = fmaxf(fmaf(acc[0], iv, bl0.x), 0.f);
  r[1] = fmaxf(fmaf(acc[1], iv, bl0.y), 0.f);
  r[2] = fmaxf(fmaf(acc[2], iv, bl0.z), 0.f);
  r[3] = fmaxf(fmaf(acc[3], iv, bl0.w), 0.f);
  r[4] = fmaxf(fmaf(acc[4], iv, bl1.x), 0.f);
  r[5] = fmaxf(fmaf(acc[5], iv, bl1.y), 0.f);
  r[6] = fmaxf(fmaf(acc[6], iv, bl1.z), 0.f);
  r[7] = fmaxf(fmaf(acc[7], iv, bl1.w), 0.f);
}

// ---------------- layer-2 aggregation + fused readout ----------------
__global__ __launch_bounds__(256) void k_spmm_out(const int* __restrict__ offs, const int* __restrict__ ssrc,
                                                  const unsigned short* __restrict__ hgb,
                                                  const float* __restrict__ als, const float* __restrict__ ald,
                                                  const float* __restrict__ bias, const float* __restrict__ Wout,
                                                  float* __restrict__ out, int n) {
  int tid = threadIdx.x, lane = tid & 63, wv = tid >> 6;
  int g8 = lane >> 3, l8 = lane & 7;
  const uint4* hg4 = (const uint4*)hgb;
  float4 bl0 = ((const float4*)bias)[l8 * 2];
  float4 bl1 = ((const float4*)bias)[l8 * 2 + 1];

  __shared__ float gsl[3];
  if (tid < 3) gsl[tid] = 0.f;

  int node = (blockIdx.x * 4 + wv) * 8 + g8;
  bool nodeok = node < n;
  int cnode = min(node, n - 1);
  float r[8];
  agg_node(node, n, offs, ssrc, hg4, als, ald, bl0, bl1, l8, r);

  int node0 = blockIdx.x * 32;
  int grp0 = node0 / 20;
  int grp = cnode / 20, slot = cnode - grp * 20;
  const float* wr = Wout + slot * F + l8 * 8;
  float dot = 0.f;
  #pragma unroll
  for (int k = 0; k < 8; k++) dot = fmaf(r[k], wr[k], dot);
  #pragma unroll
  for (int o = 1; o <= 4; o <<= 1) dot += __shfl_xor(dot, o);  // within subgroup
  __syncthreads();
  if (nodeok && l8 == 0) atomicAdd(&gsl[grp - grp0], dot);
  __syncthreads();
  if (tid < 3) {
    float v = gsl[tid];
    if (v != 0.f) atomicAdd(out + grp0 + tid, v);
  }
}

// ---------------- launch ----------------
extern "C" void kernel_launch(void* const* d_in, const int* in_sizes, int n_in,
                              void* d_out, int out_size, void* d_ws, size_t ws_size,
                              hipStream_t stream) {
  const float* x   = (const float*)d_in[0];
  const int*   ei  = (const int*)d_in[1];
  const float* W1  = (const float*)d_in[2];
  const float* as1 = (const float*)d_in[3];
  const float* ad1 = (const float*)d_in[4];
  const float* b1  = (const float*)d_in[5];
  const float* W2  = (const float*)d_in[6];
  const float* as2 = (const float*)d_in[7];
  const float* ad2 = (const float*)d_in[8];
  const float* b2  = (const float*)d_in[9];
  const float* Wo  = (const float*)d_in[10];
  const float* bo  = (const float*)d_in[11];
  float* out = (float*)d_out;

  const int N = in_sizes[0] / F;
  const int E = in_sizes[1] / 2;
  const int* esrc = ei;
  const int* edst = ei + E;

  size_t off = 0;
  auto alloc = [&](size_t bytes) -> void* {
    void* p = (char*)d_ws + off;
    off += (bytes + 255) & ~(size_t)255;
    return p;
  };
  unsigned short* hgb  = (unsigned short*)alloc((size_t)N * F * 2);  // layer-1 h (bf16)
  unsigned short* hgb2 = (unsigned short*)alloc((size_t)N * F * 2);  // layer-2 h (bf16)
  float* als  = (float*)alloc((size_t)N * 4);
  float* ald  = (float*)alloc((size_t)N * 4);
  float* als2 = (float*)alloc((size_t)N * 4);
  float* ald2 = (float*)alloc((size_t)N * 4);
  int* offs   = (int*)alloc((size_t)(N + 1) * 4);
  int* bcnt   = (int*)alloc((size_t)1024 * 16 * 4);  // per-bucket counters, 64B-padded
  int* ssrc   = (int*)alloc((size_t)(E + 64) * 4);   // CSR src lists (edges only)
  unsigned int* binned = (unsigned int*)alloc((size_t)1024 * BCAP * 4);
  uint4* wf   = (uint4*)alloc(16384);                // packed W frags: 2 layers x 512 uint4
  (void)ws_size; (void)n_in; (void)out_size;

  const int NG = N / 20;
  const int NB = (N + NPB - 1) / NPB;                // 1024
  const int S = 256;                                 // scatter blocks
  const int CH = (((E + S - 1) / S) + 3) & ~3;       // chunk, multiple of 4 for int4 loads

  // W pack + counter zero + out init
  k_prep<<<2, 256, 0, stream>>>(W1, W2, wf, bcnt, NB, out, bo, NG);
  // fused: bucketed scatter (S blocks) + layer-1 GEMM (N/64 blocks)
  k_scatter_gemm1<<<S + (N >> 6), 256, 0, stream>>>(esrc, edst, bcnt, binned, E, CH, S,
                                                    x, wf, as1, ad1, hgb, als, ald, N);
  // fused: per-bucket CSR build + layer-1 aggregation + layer-2 GEMM
  k_csr_g2<<<NB, 256, 0, stream>>>(binned, bcnt, ssrc, offs, hgb, als, ald, b1,
                                   wf + 512, as2, ad2, hgb2, als2, ald2, N, NB);
  // layer-2 aggregation + fused readout
  k_spmm_out<<<(N >> 5), 256, 0, stream>>>(offs, ssrc, hgb2, als2, ald2, b2, Wo, out, N);
}